// Round 3
// baseline (1611.855 us; speedup 1.0000x reference)
//
#include <hip/hip_runtime.h>

#define N_ELEM 262144   // 1*512*512 per batch image
#define SPLIT 32        // blocks per (batch,tensor) pair for the scan kernels
#define NTS 256         // scan-kernel block size
#define NCOPY 16        // LDS histogram replication
#define CAPG_MAX 16384  // per-pair global candidate cap
#define TIE_CAP 512

// Order-preserving float->uint key: larger float => larger key.
__device__ __forceinline__ unsigned keyOf(float f) {
    unsigned u = __float_as_uint(f);
    return (u & 0x80000000u) ? ~u : (u | 0x80000000u);
}

__device__ __forceinline__ const float* pairSrc(int p, const float* rv, const float* ri, const float* rf) {
    int t = p % 3, b = p / 3;
    return (t == 0 ? rv : (t == 1 ? ri : rf)) + (size_t)b * N_ELEM;
}

// ---- Kernel A: per-slice 8-bit MSB histogram -> global hist[pair*256+bin] ----
__global__ __launch_bounds__(NTS) void hist_kernel(const float* __restrict__ rv,
                                                   const float* __restrict__ ri,
                                                   const float* __restrict__ rf,
                                                   int* __restrict__ hist) {
    const int p = blockIdx.x / SPLIT;
    const int s = blockIdx.x % SPLIT;
    const float4* p4 = (const float4*)pairSrc(p, rv, ri, rf) + (size_t)s * (N_ELEM / 4 / SPLIT);

    __shared__ unsigned h[256 * NCOPY];   // 16 KB
    const int tid = threadIdx.x;
    const int copy = tid & (NCOPY - 1);
    for (int i = tid; i < 256 * NCOPY; i += NTS) h[i] = 0;
    __syncthreads();

    for (int i = tid; i < N_ELEM / 4 / SPLIT; i += NTS) {
        float4 v = p4[i];
        atomicAdd(&h[(keyOf(v.x) >> 24) * NCOPY + copy], 1u);
        atomicAdd(&h[(keyOf(v.y) >> 24) * NCOPY + copy], 1u);
        atomicAdd(&h[(keyOf(v.z) >> 24) * NCOPY + copy], 1u);
        atomicAdd(&h[(keyOf(v.w) >> 24) * NCOPY + copy], 1u);
    }
    __syncthreads();
    if (tid < 256) {
        unsigned sum = 0;
        for (int c = 0; c < NCOPY; ++c) sum += h[tid * NCOPY + c];
        if (sum) atomicAdd(&hist[p * 256 + tid], (int)sum);
    }
}

// ---- Kernel B: collect all elements whose top-8-bit bin >= the pair's
//      threshold bin into the per-pair global candidate buffer ----
__global__ __launch_bounds__(NTS) void collect_kernel(const float* __restrict__ rv,
                                                      const float* __restrict__ ri,
                                                      const float* __restrict__ rf,
                                                      const int* __restrict__ hist,
                                                      int* __restrict__ cnt,
                                                      unsigned long long* __restrict__ cand,
                                                      int capg) {
    const int p = blockIdx.x / SPLIT;
    const int s = blockIdx.x % SPLIT;
    const int t = p % 3;
    const int K = (t == 2) ? 360 : 180;
    const float4* p4 = (const float4*)pairSrc(p, rv, ri, rf) + (size_t)s * (N_ELEM / 4 / SPLIT);

    __shared__ unsigned suf[257];
    __shared__ int s_selbin;
    const int tid = threadIdx.x;

    // parallel suffix-scan of the 256-bin hist to find the K-th bin
    if (tid < 256) suf[tid] = (unsigned)hist[p * 256 + tid];
    __syncthreads();
    for (int off = 1; off < 256; off <<= 1) {
        unsigned add = (tid < 256 && tid + off < 256) ? suf[tid + off] : 0u;
        __syncthreads();
        if (tid < 256) suf[tid] += add;
        __syncthreads();
    }
    if (tid < 256) {
        unsigned below = (tid == 255) ? 0u : suf[tid + 1];
        if (suf[tid] >= (unsigned)K && below < (unsigned)K) s_selbin = tid;
    }
    __syncthreads();
    const unsigned selbin = (unsigned)s_selbin;

    unsigned long long* mycand = cand + (size_t)p * capg;
    const int base = s * (N_ELEM / SPLIT);
    for (int i = tid; i < N_ELEM / 4 / SPLIT; i += NTS) {
        float4 v = p4[i];
        unsigned kk; int pos;
        kk = keyOf(v.x); if ((kk >> 24) >= selbin) { pos = atomicAdd(&cnt[p], 1); if (pos < capg) mycand[pos] = ((unsigned long long)kk << 32) | (unsigned)(base + 4 * i + 0); }
        kk = keyOf(v.y); if ((kk >> 24) >= selbin) { pos = atomicAdd(&cnt[p], 1); if (pos < capg) mycand[pos] = ((unsigned long long)kk << 32) | (unsigned)(base + 4 * i + 1); }
        kk = keyOf(v.z); if ((kk >> 24) >= selbin) { pos = atomicAdd(&cnt[p], 1); if (pos < capg) mycand[pos] = ((unsigned long long)kk << 32) | (unsigned)(base + 4 * i + 2); }
        kk = keyOf(v.w); if ((kk >> 24) >= selbin) { pos = atomicAdd(&cnt[p], 1); if (pos < capg) mycand[pos] = ((unsigned long long)kk << 32) | (unsigned)(base + 4 * i + 3); }
    }
}

// ---- Kernel C: exact rank-K radix select per pair; emit K indices ----
__global__ __launch_bounds__(NTS) void select_kernel(const float* __restrict__ rv,
                                                     const float* __restrict__ ri,
                                                     const float* __restrict__ rf,
                                                     const int* __restrict__ cnt,
                                                     const unsigned long long* __restrict__ cand,
                                                     int capg,
                                                     int* __restrict__ idx_out) {
    const int p = blockIdx.x;
    const int t = p % 3;
    const int K = (t == 2) ? 360 : 180;
    int* obuf = idx_out + (size_t)p * 360;
    const unsigned long long* mycand = cand + (size_t)p * capg;
    const float4* p4 = (const float4*)pairSrc(p, rv, ri, rf);

    __shared__ unsigned suf[257];
    __shared__ int ties[TIE_CAP];
    __shared__ unsigned s_p2; __shared__ int s_b2; __shared__ int s_cg2;
    __shared__ int s_on; __shared__ int s_tn;
    const int tid = threadIdx.x;

    const int cn = cnt[p];
    const bool fits = (cn <= capg);

    if (tid == 0) { s_p2 = 0; s_b2 = 0; s_cg2 = 0; }
    __syncthreads();

    // 4 passes x 8 bits: refine the rank-K key prefix
    while (s_b2 < 32) {
        if (tid < 256) suf[tid] = 0;
        __syncthreads();
        {
            const int b2 = s_b2; const unsigned p2 = s_p2;
            const int sh2 = 24 - b2;
            if (fits) {
                for (int i = tid; i < cn; i += NTS) {
                    unsigned kk = (unsigned)(mycand[i] >> 32);
                    bool match = (b2 == 0) || ((kk >> (32 - b2)) == p2);
                    if (match) atomicAdd(&suf[(kk >> sh2) & 255u], 1u);
                }
            } else {   // fallback: scan the full image (degenerate inputs only)
                for (int i = tid; i < N_ELEM / 4; i += NTS) {
                    float4 v = p4[i];
                    unsigned kk;
                    kk = keyOf(v.x); if ((b2 == 0) || ((kk >> (32 - b2)) == p2)) atomicAdd(&suf[(kk >> sh2) & 255u], 1u);
                    kk = keyOf(v.y); if ((b2 == 0) || ((kk >> (32 - b2)) == p2)) atomicAdd(&suf[(kk >> sh2) & 255u], 1u);
                    kk = keyOf(v.z); if ((b2 == 0) || ((kk >> (32 - b2)) == p2)) atomicAdd(&suf[(kk >> sh2) & 255u], 1u);
                    kk = keyOf(v.w); if ((b2 == 0) || ((kk >> (32 - b2)) == p2)) atomicAdd(&suf[(kk >> sh2) & 255u], 1u);
                }
            }
        }
        __syncthreads();
        // parallel suffix-scan + winner pick
        for (int off = 1; off < 256; off <<= 1) {
            unsigned add = (tid < 256 && tid + off < 256) ? suf[tid + off] : 0u;
            __syncthreads();
            if (tid < 256) suf[tid] += add;
            __syncthreads();
        }
        {
            const unsigned r = (unsigned)(K - s_cg2);
            __syncthreads();
            if (tid < 256) {
                unsigned below = (tid == 255) ? 0u : suf[tid + 1];
                if (suf[tid] >= r && below < r) {
                    s_p2 = (s_p2 << 8) | (unsigned)tid;
                    s_b2 += 8;
                    s_cg2 += (int)below;
                }
            }
        }
        __syncthreads();
    }

    if (tid == 0) { s_on = 0; s_tn = 0; }
    __syncthreads();

    // emit: key > Kth directly; key == Kth to tie buffer
    {
        const unsigned Kth = s_p2;
        if (fits) {
            for (int i = tid; i < cn; i += NTS) {
                unsigned long long e = mycand[i];
                unsigned kk = (unsigned)(e >> 32);
                int idx = (int)(e & 0xffffffffu);
                if (kk > Kth) { int pos = atomicAdd(&s_on, 1); obuf[pos] = idx; }
                else if (kk == Kth) { int pos = atomicAdd(&s_tn, 1); if (pos < TIE_CAP) ties[pos] = idx; }
            }
        } else {
            for (int i = tid; i < N_ELEM / 4; i += NTS) {
                float4 v = p4[i];
                float vals[4] = {v.x, v.y, v.z, v.w};
                for (int c = 0; c < 4; ++c) {
                    unsigned kk = keyOf(vals[c]);
                    if (kk > Kth) { int pos = atomicAdd(&s_on, 1); obuf[pos] = 4 * i + c; }
                    else if (kk == Kth) { int pos = atomicAdd(&s_tn, 1); if (pos < TIE_CAP) ties[pos] = 4 * i + c; }
                }
            }
        }
    }
    __syncthreads();
    if (tid == 0) {
        int need = K - s_cg2;                       // tie slots to fill (>=1)
        int tn = s_tn; if (tn > TIE_CAP) tn = TIE_CAP;
        int rr = need; if (rr > tn) rr = tn;        // safety clamp (degenerate only)
        for (int a = 0; a < rr; ++a) {              // selection sort: rr smallest indices
            int mb = a;
            for (int j = a + 1; j < tn; ++j) if (ties[j] < ties[mb]) mb = j;
            int tmp = ties[a]; ties[a] = ties[mb]; ties[mb] = tmp;
            obuf[s_on + a] = ties[a];
        }
        for (int a = rr; a < need; ++a) obuf[s_on + a] = (tn > 0) ? ties[0] : 0;
    }
}

// One block per batch: union(rv,ri) dedupe + Chebyshev<=3 coverage vs rf set.
__global__ __launch_bounds__(256) void coverage_kernel(const int* __restrict__ idx_buf,
                                                       float* __restrict__ out,
                                                       float inv_b) {
    const int b = blockIdx.x;
    __shared__ int cnd[360];
    __shared__ int fy[360];
    __shared__ int fx[360];
    __shared__ int s_u, s_c;
    const int* rvI = idx_buf + (size_t)(b * 3 + 0) * 360;
    const int* riI = idx_buf + (size_t)(b * 3 + 1) * 360;
    const int* rfI = idx_buf + (size_t)(b * 3 + 2) * 360;
    const int tid = threadIdx.x;

    for (int i = tid; i < 180; i += blockDim.x) { cnd[i] = rvI[i]; cnd[180 + i] = riI[i]; }
    for (int i = tid; i < 360; i += blockDim.x) { int v = rfI[i]; fy[i] = v >> 9; fx[i] = v & 511; }
    if (tid == 0) { s_u = 0; s_c = 0; }
    __syncthreads();

    for (int i = tid; i < 360; i += blockDim.x) {
        int v = cnd[i];
        bool dup = false;
        for (int j = 0; j < i; ++j) if (cnd[j] == v) { dup = true; break; }
        if (!dup) {
            atomicAdd(&s_u, 1);
            int y = v >> 9, x = v & 511;
            bool cov = false;
            for (int j = 0; j < 360; ++j) {
                int dy = y - fy[j]; if (dy < 0) dy = -dy;
                int dx = x - fx[j]; if (dx < 0) dx = -dx;
                if (dy <= 3 && dx <= 3) { cov = true; break; }
            }
            if (cov) atomicAdd(&s_c, 1);
        }
    }
    __syncthreads();
    if (tid == 0) {
        float denom = (float)(s_u > 0 ? s_u : 1);
        float loss = 1.0f - (float)s_c / denom;
        atomicAdd(out, loss * inv_b);
    }
}

extern "C" void kernel_launch(void* const* d_in, const int* in_sizes, int n_in,
                              void* d_out, int out_size, void* d_ws, size_t ws_size,
                              hipStream_t stream) {
    const float* rv = (const float*)d_in[0];
    const float* ri = (const float*)d_in[1];
    const float* rf = (const float*)d_in[2];
    float* out = (float*)d_out;

    const int B = in_sizes[0] / N_ELEM;
    const int P = 3 * B;

    // workspace layout
    char* ws = (char*)d_ws;
    int* hist = (int*)ws;                                    // P*256 ints
    int* cnt  = (int*)(ws + (size_t)P * 256 * 4);            // P ints
    int* idx_buf = (int*)(ws + (size_t)P * 257 * 4);         // P*360 ints
    size_t fixed = (size_t)P * 257 * 4 + (size_t)P * 360 * 4;
    fixed = (fixed + 7) & ~(size_t)7;
    unsigned long long* cand = (unsigned long long*)(ws + fixed);
    size_t avail = (ws_size > fixed) ? (ws_size - fixed) / ((size_t)P * 8) : 0;
    int capg = (int)(avail < CAPG_MAX ? avail : CAPG_MAX);   // 0 => select falls back

    hipMemsetAsync(hist, 0, (size_t)P * 257 * 4, stream);    // hist + cnt
    hipMemsetAsync(d_out, 0, sizeof(float), stream);
    hist_kernel<<<P * SPLIT, NTS, 0, stream>>>(rv, ri, rf, hist);
    collect_kernel<<<P * SPLIT, NTS, 0, stream>>>(rv, ri, rf, hist, cnt, cand, capg);
    select_kernel<<<P, NTS, 0, stream>>>(rv, ri, rf, cnt, cand, capg, idx_buf);
    coverage_kernel<<<B, 256, 0, stream>>>(idx_buf, out, 1.0f / (float)B);
}

// Round 4
// 231.191 us; speedup vs baseline: 6.9720x; 6.9720x over previous
//
#include <hip/hip_runtime.h>

#define N_ELEM 262144   // 1*512*512 per batch image
#define SPLIT 32        // blocks per (batch,tensor) pair in collect
#define NTS 256         // block size
#define CAPG_MAX 8192   // per-pair global candidate cap
#define LCAP 2048       // per-block LDS staging entries (expected ~51 used)
#define TIE_CAP 512
#define THRESH 2.5f     // fixed pre-filter; select falls back if it miscounts

// Order-preserving float->uint key: larger float => larger key.
__device__ __forceinline__ unsigned keyOf(float f) {
    unsigned u = __float_as_uint(f);
    return (u & 0x80000000u) ? ~u : (u | 0x80000000u);
}

__device__ __forceinline__ const float* pairSrc(int p, const float* rv, const float* ri, const float* rf) {
    int t = p % 3, b = p / 3;
    return (t == 0 ? rv : (t == 1 ? ri : rf)) + (size_t)b * N_ELEM;
}

// ---- Kernel 1: threshold-filter candidates into per-pair global buffers.
//      LDS staging; exactly ONE returning global atomic per block. ----
__global__ __launch_bounds__(NTS) void collect_kernel(const float* __restrict__ rv,
                                                      const float* __restrict__ ri,
                                                      const float* __restrict__ rf,
                                                      int* __restrict__ cnt,
                                                      unsigned long long* __restrict__ cand,
                                                      int capg) {
    const int p = blockIdx.x / SPLIT;
    const int s = blockIdx.x % SPLIT;
    const float4* p4 = (const float4*)pairSrc(p, rv, ri, rf) + (size_t)s * (N_ELEM / 4 / SPLIT);

    __shared__ unsigned long long buf[LCAP];   // 16 KB
    __shared__ int s_m, s_base;
    const int tid = threadIdx.x;
    if (tid == 0) s_m = 0;
    __syncthreads();

    const int base_idx = s * (N_ELEM / SPLIT);
    for (int i = tid; i < N_ELEM / 4 / SPLIT; i += NTS) {
        float4 v = p4[i];
        int pos;
        if (v.x > THRESH) { pos = atomicAdd(&s_m, 1); if (pos < LCAP) buf[pos] = ((unsigned long long)keyOf(v.x) << 32) | (unsigned)(base_idx + 4 * i + 0); }
        if (v.y > THRESH) { pos = atomicAdd(&s_m, 1); if (pos < LCAP) buf[pos] = ((unsigned long long)keyOf(v.y) << 32) | (unsigned)(base_idx + 4 * i + 1); }
        if (v.z > THRESH) { pos = atomicAdd(&s_m, 1); if (pos < LCAP) buf[pos] = ((unsigned long long)keyOf(v.z) << 32) | (unsigned)(base_idx + 4 * i + 2); }
        if (v.w > THRESH) { pos = atomicAdd(&s_m, 1); if (pos < LCAP) buf[pos] = ((unsigned long long)keyOf(v.w) << 32) | (unsigned)(base_idx + 4 * i + 3); }
    }
    __syncthreads();

    int m = s_m;
    const bool over = (m > LCAP);
    if (over) m = LCAP;
    if (tid == 0) {
        // If LDS overflowed we lost entries: poison cnt so select falls back.
        int add = over ? (m + capg + 1) : m;
        s_base = atomicAdd(&cnt[p], add);
    }
    __syncthreads();

    const int base = s_base;
    unsigned long long* mycand = cand + (size_t)p * capg;
    for (int i = tid; i < m; i += NTS) {
        int pos = base + i;
        if (pos < capg) mycand[pos] = buf[i];
    }
}

// ---- Kernel 2: exact rank-K radix select per pair; emit K indices.
//      Falls back to full-image scan if the candidate set is invalid. ----
__global__ __launch_bounds__(NTS) void select_kernel(const float* __restrict__ rv,
                                                     const float* __restrict__ ri,
                                                     const float* __restrict__ rf,
                                                     const int* __restrict__ cnt,
                                                     const unsigned long long* __restrict__ cand,
                                                     int capg,
                                                     int* __restrict__ idx_out) {
    const int p = blockIdx.x;
    const int t = p % 3;
    const int K = (t == 2) ? 360 : 180;
    int* obuf = idx_out + (size_t)p * 360;
    const unsigned long long* mycand = cand + (size_t)p * capg;
    const float4* p4 = (const float4*)pairSrc(p, rv, ri, rf);

    __shared__ unsigned suf[257];
    __shared__ int ties[TIE_CAP];
    __shared__ unsigned s_p2; __shared__ int s_b2; __shared__ int s_cg2;
    __shared__ int s_on; __shared__ int s_tn;
    const int tid = threadIdx.x;

    const int cn = cnt[p];
    const bool fits = (cn >= K) && (cn <= capg);   // threshold filter valid?

    if (tid == 0) { s_p2 = 0; s_b2 = 0; s_cg2 = 0; }
    __syncthreads();

    // 4 passes x 8 bits: refine the rank-K key prefix
    while (s_b2 < 32) {
        if (tid < 256) suf[tid] = 0;
        __syncthreads();
        {
            const int b2 = s_b2; const unsigned p2 = s_p2;
            const int sh2 = 24 - b2;
            if (fits) {
                for (int i = tid; i < cn; i += NTS) {
                    unsigned kk = (unsigned)(mycand[i] >> 32);
                    bool match = (b2 == 0) || ((kk >> (32 - b2)) == p2);
                    if (match) atomicAdd(&suf[(kk >> sh2) & 255u], 1u);
                }
            } else {   // fallback: scan the full image (degenerate inputs only)
                for (int i = tid; i < N_ELEM / 4; i += NTS) {
                    float4 v = p4[i];
                    unsigned kk;
                    kk = keyOf(v.x); if ((b2 == 0) || ((kk >> (32 - b2)) == p2)) atomicAdd(&suf[(kk >> sh2) & 255u], 1u);
                    kk = keyOf(v.y); if ((b2 == 0) || ((kk >> (32 - b2)) == p2)) atomicAdd(&suf[(kk >> sh2) & 255u], 1u);
                    kk = keyOf(v.z); if ((b2 == 0) || ((kk >> (32 - b2)) == p2)) atomicAdd(&suf[(kk >> sh2) & 255u], 1u);
                    kk = keyOf(v.w); if ((b2 == 0) || ((kk >> (32 - b2)) == p2)) atomicAdd(&suf[(kk >> sh2) & 255u], 1u);
                }
            }
        }
        __syncthreads();
        // parallel suffix-scan + winner pick
        for (int off = 1; off < 256; off <<= 1) {
            unsigned add = (tid < 256 && tid + off < 256) ? suf[tid + off] : 0u;
            __syncthreads();
            if (tid < 256) suf[tid] += add;
            __syncthreads();
        }
        {
            const unsigned r = (unsigned)(K - s_cg2);
            __syncthreads();
            if (tid < 256) {
                unsigned below = (tid == 255) ? 0u : suf[tid + 1];
                if (suf[tid] >= r && below < r) {
                    s_p2 = (s_p2 << 8) | (unsigned)tid;
                    s_b2 += 8;
                    s_cg2 += (int)below;
                }
            }
        }
        __syncthreads();
    }

    if (tid == 0) { s_on = 0; s_tn = 0; }
    __syncthreads();

    // emit: key > Kth directly; key == Kth to tie buffer
    {
        const unsigned Kth = s_p2;
        if (fits) {
            for (int i = tid; i < cn; i += NTS) {
                unsigned long long e = mycand[i];
                unsigned kk = (unsigned)(e >> 32);
                int idx = (int)(e & 0xffffffffu);
                if (kk > Kth) { int pos = atomicAdd(&s_on, 1); obuf[pos] = idx; }
                else if (kk == Kth) { int pos = atomicAdd(&s_tn, 1); if (pos < TIE_CAP) ties[pos] = idx; }
            }
        } else {
            for (int i = tid; i < N_ELEM / 4; i += NTS) {
                float4 v = p4[i];
                float vals[4] = {v.x, v.y, v.z, v.w};
                for (int c = 0; c < 4; ++c) {
                    unsigned kk = keyOf(vals[c]);
                    if (kk > Kth) { int pos = atomicAdd(&s_on, 1); obuf[pos] = 4 * i + c; }
                    else if (kk == Kth) { int pos = atomicAdd(&s_tn, 1); if (pos < TIE_CAP) ties[pos] = 4 * i + c; }
                }
            }
        }
    }
    __syncthreads();
    if (tid == 0) {
        int need = K - s_cg2;                       // tie slots to fill (>=1)
        int tn = s_tn; if (tn > TIE_CAP) tn = TIE_CAP;
        int rr = need; if (rr > tn) rr = tn;        // safety clamp (degenerate only)
        for (int a = 0; a < rr; ++a) {              // selection sort: rr smallest indices
            int mb = a;
            for (int j = a + 1; j < tn; ++j) if (ties[j] < ties[mb]) mb = j;
            int tmp = ties[a]; ties[a] = ties[mb]; ties[mb] = tmp;
            obuf[s_on + a] = ties[a];
        }
        for (int a = rr; a < need; ++a) obuf[s_on + a] = (tn > 0) ? ties[0] : 0;
    }
}

// One block per batch: union(rv,ri) dedupe + Chebyshev<=3 coverage vs rf set.
__global__ __launch_bounds__(256) void coverage_kernel(const int* __restrict__ idx_buf,
                                                       float* __restrict__ out,
                                                       float inv_b) {
    const int b = blockIdx.x;
    __shared__ int cnd[360];
    __shared__ int fy[360];
    __shared__ int fx[360];
    __shared__ int s_u, s_c;
    const int* rvI = idx_buf + (size_t)(b * 3 + 0) * 360;
    const int* riI = idx_buf + (size_t)(b * 3 + 1) * 360;
    const int* rfI = idx_buf + (size_t)(b * 3 + 2) * 360;
    const int tid = threadIdx.x;

    for (int i = tid; i < 180; i += blockDim.x) { cnd[i] = rvI[i]; cnd[180 + i] = riI[i]; }
    for (int i = tid; i < 360; i += blockDim.x) { int v = rfI[i]; fy[i] = v >> 9; fx[i] = v & 511; }
    if (tid == 0) { s_u = 0; s_c = 0; }
    __syncthreads();

    for (int i = tid; i < 360; i += blockDim.x) {
        int v = cnd[i];
        bool dup = false;
        for (int j = 0; j < i; ++j) if (cnd[j] == v) { dup = true; break; }
        if (!dup) {
            atomicAdd(&s_u, 1);
            int y = v >> 9, x = v & 511;
            bool cov = false;
            for (int j = 0; j < 360; ++j) {
                int dy = y - fy[j]; if (dy < 0) dy = -dy;
                int dx = x - fx[j]; if (dx < 0) dx = -dx;
                if (dy <= 3 && dx <= 3) { cov = true; break; }
            }
            if (cov) atomicAdd(&s_c, 1);
        }
    }
    __syncthreads();
    if (tid == 0) {
        float denom = (float)(s_u > 0 ? s_u : 1);
        float loss = 1.0f - (float)s_c / denom;
        atomicAdd(out, loss * inv_b);
    }
}

extern "C" void kernel_launch(void* const* d_in, const int* in_sizes, int n_in,
                              void* d_out, int out_size, void* d_ws, size_t ws_size,
                              hipStream_t stream) {
    const float* rv = (const float*)d_in[0];
    const float* ri = (const float*)d_in[1];
    const float* rf = (const float*)d_in[2];
    float* out = (float*)d_out;

    const int B = in_sizes[0] / N_ELEM;
    const int P = 3 * B;

    // workspace layout: cnt (P ints) | idx_buf (P*360 ints) | cand (P*capg u64)
    char* ws = (char*)d_ws;
    int* cnt = (int*)ws;
    int* idx_buf = (int*)(ws + (size_t)P * 4);
    size_t fixed = (size_t)P * 4 + (size_t)P * 360 * 4;
    fixed = (fixed + 7) & ~(size_t)7;
    unsigned long long* cand = (unsigned long long*)(ws + fixed);
    size_t avail = (ws_size > fixed) ? (ws_size - fixed) / ((size_t)P * 8) : 0;
    int capg = (int)(avail < CAPG_MAX ? avail : CAPG_MAX);   // 0 => select falls back

    hipMemsetAsync(cnt, 0, (size_t)P * 4, stream);
    hipMemsetAsync(d_out, 0, sizeof(float), stream);
    collect_kernel<<<P * SPLIT, NTS, 0, stream>>>(rv, ri, rf, cnt, cand, capg);
    select_kernel<<<P, NTS, 0, stream>>>(rv, ri, rf, cnt, cand, capg, idx_buf);
    coverage_kernel<<<B, 256, 0, stream>>>(idx_buf, out, 1.0f / (float)B);
}

// Round 5
// 175.156 us; speedup vs baseline: 9.2024x; 1.3199x over previous
//
#include <hip/hip_runtime.h>

#define N_ELEM 262144   // 1*512*512 per batch image
#define SPLIT 32        // blocks per (batch,tensor) pair in collect
#define NTS 256         // block size
#define CAPG_MAX 8192   // per-pair global candidate cap
#define LCAP 2048       // per-block LDS staging entries (expected ~51 used)
#define TIE_CAP 512
#define THRESH 2.5f     // fixed pre-filter; select falls back if it miscounts

// Order-preserving float->uint key: larger float => larger key.
__device__ __forceinline__ unsigned keyOf(float f) {
    unsigned u = __float_as_uint(f);
    return (u & 0x80000000u) ? ~u : (u | 0x80000000u);
}

__device__ __forceinline__ const float* pairSrc(int p, const float* rv, const float* ri, const float* rf) {
    int t = p % 3, b = p / 3;
    return (t == 0 ? rv : (t == 1 ? ri : rf)) + (size_t)b * N_ELEM;
}

// ---- Kernel 0: zero the pair counters and the output scalar ----
__global__ void zero_kernel(int* __restrict__ cnt, int P, float* __restrict__ out) {
    int i = threadIdx.x + blockIdx.x * blockDim.x;
    if (i < P) cnt[i] = 0;
    if (i == 0) *out = 0.0f;
}

// ---- Kernel 1: threshold-filter candidates into per-pair global buffers.
//      LDS staging; exactly ONE returning global atomic per block. ----
__global__ __launch_bounds__(NTS) void collect_kernel(const float* __restrict__ rv,
                                                      const float* __restrict__ ri,
                                                      const float* __restrict__ rf,
                                                      int* __restrict__ cnt,
                                                      unsigned long long* __restrict__ cand,
                                                      int capg) {
    const int p = blockIdx.x / SPLIT;
    const int s = blockIdx.x % SPLIT;
    const float4* p4 = (const float4*)pairSrc(p, rv, ri, rf) + (size_t)s * (N_ELEM / 4 / SPLIT);

    __shared__ unsigned long long buf[LCAP];   // 16 KB
    __shared__ int s_m, s_base;
    const int tid = threadIdx.x;
    if (tid == 0) s_m = 0;
    __syncthreads();

    const int base_idx = s * (N_ELEM / SPLIT);
    for (int i = tid; i < N_ELEM / 4 / SPLIT; i += NTS) {
        float4 v = p4[i];
        int pos;
        if (v.x > THRESH) { pos = atomicAdd(&s_m, 1); if (pos < LCAP) buf[pos] = ((unsigned long long)keyOf(v.x) << 32) | (unsigned)(base_idx + 4 * i + 0); }
        if (v.y > THRESH) { pos = atomicAdd(&s_m, 1); if (pos < LCAP) buf[pos] = ((unsigned long long)keyOf(v.y) << 32) | (unsigned)(base_idx + 4 * i + 1); }
        if (v.z > THRESH) { pos = atomicAdd(&s_m, 1); if (pos < LCAP) buf[pos] = ((unsigned long long)keyOf(v.z) << 32) | (unsigned)(base_idx + 4 * i + 2); }
        if (v.w > THRESH) { pos = atomicAdd(&s_m, 1); if (pos < LCAP) buf[pos] = ((unsigned long long)keyOf(v.w) << 32) | (unsigned)(base_idx + 4 * i + 3); }
    }
    __syncthreads();

    int m = s_m;
    const bool over = (m > LCAP);
    if (over) m = LCAP;
    if (tid == 0) {
        // If LDS overflowed we lost entries: poison cnt so select falls back.
        int add = over ? (m + capg + 1) : m;
        s_base = atomicAdd(&cnt[p], add);
    }
    __syncthreads();

    const int base = s_base;
    unsigned long long* mycand = cand + (size_t)p * capg;
    for (int i = tid; i < m; i += NTS) {
        int pos = base + i;
        if (pos < capg) mycand[pos] = buf[i];
    }
}

// ---- Kernel 2: exact rank-K radix select per pair; emit K indices.
//      Falls back to full-image scan if the candidate set is invalid. ----
__global__ __launch_bounds__(NTS) void select_kernel(const float* __restrict__ rv,
                                                     const float* __restrict__ ri,
                                                     const float* __restrict__ rf,
                                                     const int* __restrict__ cnt,
                                                     const unsigned long long* __restrict__ cand,
                                                     int capg,
                                                     int* __restrict__ idx_out) {
    const int p = blockIdx.x;
    const int t = p % 3;
    const int K = (t == 2) ? 360 : 180;
    int* obuf = idx_out + (size_t)p * 360;
    const unsigned long long* mycand = cand + (size_t)p * capg;
    const float4* p4 = (const float4*)pairSrc(p, rv, ri, rf);

    __shared__ unsigned suf[257];
    __shared__ int ties[TIE_CAP];
    __shared__ unsigned s_p2; __shared__ int s_b2; __shared__ int s_cg2;
    __shared__ int s_on; __shared__ int s_tn;
    const int tid = threadIdx.x;

    const int cn = cnt[p];
    const bool fits = (cn >= K) && (cn <= capg);   // threshold filter valid?

    if (tid == 0) { s_p2 = 0; s_b2 = 0; s_cg2 = 0; }
    __syncthreads();

    // 4 passes x 8 bits: refine the rank-K key prefix
    while (s_b2 < 32) {
        if (tid < 256) suf[tid] = 0;
        __syncthreads();
        {
            const int b2 = s_b2; const unsigned p2 = s_p2;
            const int sh2 = 24 - b2;
            if (fits) {
                for (int i = tid; i < cn; i += NTS) {
                    unsigned kk = (unsigned)(mycand[i] >> 32);
                    bool match = (b2 == 0) || ((kk >> (32 - b2)) == p2);
                    if (match) atomicAdd(&suf[(kk >> sh2) & 255u], 1u);
                }
            } else {   // fallback: scan the full image (degenerate inputs only)
                for (int i = tid; i < N_ELEM / 4; i += NTS) {
                    float4 v = p4[i];
                    unsigned kk;
                    kk = keyOf(v.x); if ((b2 == 0) || ((kk >> (32 - b2)) == p2)) atomicAdd(&suf[(kk >> sh2) & 255u], 1u);
                    kk = keyOf(v.y); if ((b2 == 0) || ((kk >> (32 - b2)) == p2)) atomicAdd(&suf[(kk >> sh2) & 255u], 1u);
                    kk = keyOf(v.z); if ((b2 == 0) || ((kk >> (32 - b2)) == p2)) atomicAdd(&suf[(kk >> sh2) & 255u], 1u);
                    kk = keyOf(v.w); if ((b2 == 0) || ((kk >> (32 - b2)) == p2)) atomicAdd(&suf[(kk >> sh2) & 255u], 1u);
                }
            }
        }
        __syncthreads();
        // parallel suffix-scan + winner pick
        for (int off = 1; off < 256; off <<= 1) {
            unsigned add = (tid < 256 && tid + off < 256) ? suf[tid + off] : 0u;
            __syncthreads();
            if (tid < 256) suf[tid] += add;
            __syncthreads();
        }
        {
            const unsigned r = (unsigned)(K - s_cg2);
            __syncthreads();
            if (tid < 256) {
                unsigned below = (tid == 255) ? 0u : suf[tid + 1];
                if (suf[tid] >= r && below < r) {
                    s_p2 = (s_p2 << 8) | (unsigned)tid;
                    s_b2 += 8;
                    s_cg2 += (int)below;
                }
            }
        }
        __syncthreads();
    }

    if (tid == 0) { s_on = 0; s_tn = 0; }
    __syncthreads();

    // emit: key > Kth directly; key == Kth to tie buffer
    {
        const unsigned Kth = s_p2;
        if (fits) {
            for (int i = tid; i < cn; i += NTS) {
                unsigned long long e = mycand[i];
                unsigned kk = (unsigned)(e >> 32);
                int idx = (int)(e & 0xffffffffu);
                if (kk > Kth) { int pos = atomicAdd(&s_on, 1); obuf[pos] = idx; }
                else if (kk == Kth) { int pos = atomicAdd(&s_tn, 1); if (pos < TIE_CAP) ties[pos] = idx; }
            }
        } else {
            for (int i = tid; i < N_ELEM / 4; i += NTS) {
                float4 v = p4[i];
                float vals[4] = {v.x, v.y, v.z, v.w};
                for (int c = 0; c < 4; ++c) {
                    unsigned kk = keyOf(vals[c]);
                    if (kk > Kth) { int pos = atomicAdd(&s_on, 1); obuf[pos] = 4 * i + c; }
                    else if (kk == Kth) { int pos = atomicAdd(&s_tn, 1); if (pos < TIE_CAP) ties[pos] = 4 * i + c; }
                }
            }
        }
    }
    __syncthreads();
    if (tid == 0) {
        int need = K - s_cg2;                       // tie slots to fill (>=1)
        int tn = s_tn; if (tn > TIE_CAP) tn = TIE_CAP;
        int rr = need; if (rr > tn) rr = tn;        // safety clamp (degenerate only)
        for (int a = 0; a < rr; ++a) {              // selection sort: rr smallest indices
            int mb = a;
            for (int j = a + 1; j < tn; ++j) if (ties[j] < ties[mb]) mb = j;
            int tmp = ties[a]; ties[a] = ties[mb]; ties[mb] = tmp;
            obuf[s_on + a] = ties[a];
        }
        for (int a = rr; a < need; ++a) obuf[s_on + a] = (tn > 0) ? ties[0] : 0;
    }
}

// One block per batch: union(rv,ri) dedupe + Chebyshev<=3 coverage vs rf set.
// Branchless fixed-trip loops: LDS reads are unrollable (throughput-bound),
// and every lane reads the same j -> LDS broadcast, no conflicts.
__global__ __launch_bounds__(256) void coverage_kernel(const int* __restrict__ idx_buf,
                                                       float* __restrict__ out,
                                                       float inv_b) {
    const int b = blockIdx.x;
    __shared__ int cnd[360];
    __shared__ int fy[360];
    __shared__ int fx[360];
    __shared__ int s_u, s_c;
    const int* rvI = idx_buf + (size_t)(b * 3 + 0) * 360;
    const int* riI = idx_buf + (size_t)(b * 3 + 1) * 360;
    const int* rfI = idx_buf + (size_t)(b * 3 + 2) * 360;
    const int tid = threadIdx.x;

    for (int i = tid; i < 180; i += blockDim.x) { cnd[i] = rvI[i]; cnd[180 + i] = riI[i]; }
    for (int i = tid; i < 360; i += blockDim.x) { int v = rfI[i]; fy[i] = v >> 9; fx[i] = v & 511; }
    if (tid == 0) { s_u = 0; s_c = 0; }
    __syncthreads();

    int myu = 0, myc = 0;
    for (int i = tid; i < 360; i += blockDim.x) {
        const int v = cnd[i];
        const int y = v >> 9, x = v & 511;
        int dup = 0;
        #pragma unroll 8
        for (int j = 0; j < 360; ++j) dup |= (int)((j < i) & (cnd[j] == v));
        int cov = 0;
        #pragma unroll 8
        for (int j = 0; j < 360; ++j) {
            int dy = y - fy[j]; dy = (dy < 0) ? -dy : dy;
            int dx = x - fx[j]; dx = (dx < 0) ? -dx : dx;
            cov |= (int)((dy <= 3) & (dx <= 3));
        }
        if (!dup) { myu += 1; myc += cov; }
    }
    if (myu) atomicAdd(&s_u, myu);
    if (myc) atomicAdd(&s_c, myc);
    __syncthreads();
    if (tid == 0) {
        float denom = (float)(s_u > 0 ? s_u : 1);
        float loss = 1.0f - (float)s_c / denom;
        atomicAdd(out, loss * inv_b);
    }
}

extern "C" void kernel_launch(void* const* d_in, const int* in_sizes, int n_in,
                              void* d_out, int out_size, void* d_ws, size_t ws_size,
                              hipStream_t stream) {
    const float* rv = (const float*)d_in[0];
    const float* ri = (const float*)d_in[1];
    const float* rf = (const float*)d_in[2];
    float* out = (float*)d_out;

    const int B = in_sizes[0] / N_ELEM;
    const int P = 3 * B;

    // workspace layout: cnt (P ints) | idx_buf (P*360 ints) | cand (P*capg u64)
    char* ws = (char*)d_ws;
    int* cnt = (int*)ws;
    int* idx_buf = (int*)(ws + (size_t)P * 4);
    size_t fixed = (size_t)P * 4 + (size_t)P * 360 * 4;
    fixed = (fixed + 7) & ~(size_t)7;
    unsigned long long* cand = (unsigned long long*)(ws + fixed);
    size_t avail = (ws_size > fixed) ? (ws_size - fixed) / ((size_t)P * 8) : 0;
    int capg = (int)(avail < CAPG_MAX ? avail : CAPG_MAX);   // 0 => select falls back

    zero_kernel<<<1, 256, 0, stream>>>(cnt, P, out);
    collect_kernel<<<P * SPLIT, NTS, 0, stream>>>(rv, ri, rf, cnt, cand, capg);
    select_kernel<<<P, NTS, 0, stream>>>(rv, ri, rf, cnt, cand, capg, idx_buf);
    coverage_kernel<<<B, 256, 0, stream>>>(idx_buf, out, 1.0f / (float)B);
}

// Round 6
// 170.273 us; speedup vs baseline: 9.4663x; 1.0287x over previous
//
#include <hip/hip_runtime.h>

#define N_ELEM 262144   // 1*512*512 per batch image
#define SPLIT 32        // blocks per (batch,tensor) pair in collect
#define NTS 256         // block size
#define SLICE_CAP 256   // per-slice candidate cap (expected ~51, 28 sigma margin)
#define LSEL 2048       // select: LDS candidate cache entries (expected ~1630)
#define TIE_CAP 512
#define THRESH 2.5f     // fixed pre-filter; select falls back if counts invalid

// Order-preserving float->uint key: larger float => larger key.
__device__ __forceinline__ unsigned keyOf(float f) {
    unsigned u = __float_as_uint(f);
    return (u & 0x80000000u) ? ~u : (u | 0x80000000u);
}

__device__ __forceinline__ const float* pairSrc(int p, const float* rv, const float* ri, const float* rf) {
    int t = p % 3, b = p / 3;
    return (t == 0 ? rv : (t == 1 ? ri : rf)) + (size_t)b * N_ELEM;
}

// ---- Kernel 1: threshold-filter into PER-SLICE candidate regions.
//      No global atomics, no zeroing needed (counts written unconditionally).
//      Block 0 also zeroes out/done. ----
__global__ __launch_bounds__(NTS) void collect_kernel(const float* __restrict__ rv,
                                                      const float* __restrict__ ri,
                                                      const float* __restrict__ rf,
                                                      int* __restrict__ cntS,
                                                      unsigned long long* __restrict__ cand,
                                                      float* __restrict__ out,
                                                      int* __restrict__ done, int B) {
    const int p = blockIdx.x / SPLIT;
    const int s = blockIdx.x % SPLIT;
    const float4* p4 = (const float4*)pairSrc(p, rv, ri, rf) + (size_t)s * (N_ELEM / 4 / SPLIT);

    __shared__ unsigned long long buf[SLICE_CAP];   // 2 KB
    __shared__ int s_m;
    const int tid = threadIdx.x;

    if (blockIdx.x == 0) {            // once per launch: zero out + done[]
        if (tid < B) done[tid] = 0;
        if (tid == B) *out = 0.0f;
    }
    if (tid == 0) s_m = 0;
    __syncthreads();

    const int base_idx = s * (N_ELEM / SPLIT);
    for (int i = tid; i < N_ELEM / 4 / SPLIT; i += NTS) {   // 8 iterations
        float4 v = p4[i];
        int pos;
        if (v.x > THRESH) { pos = atomicAdd(&s_m, 1); if (pos < SLICE_CAP) buf[pos] = ((unsigned long long)keyOf(v.x) << 32) | (unsigned)(base_idx + 4 * i + 0); }
        if (v.y > THRESH) { pos = atomicAdd(&s_m, 1); if (pos < SLICE_CAP) buf[pos] = ((unsigned long long)keyOf(v.y) << 32) | (unsigned)(base_idx + 4 * i + 1); }
        if (v.z > THRESH) { pos = atomicAdd(&s_m, 1); if (pos < SLICE_CAP) buf[pos] = ((unsigned long long)keyOf(v.z) << 32) | (unsigned)(base_idx + 4 * i + 2); }
        if (v.w > THRESH) { pos = atomicAdd(&s_m, 1); if (pos < SLICE_CAP) buf[pos] = ((unsigned long long)keyOf(v.w) << 32) | (unsigned)(base_idx + 4 * i + 3); }
    }
    __syncthreads();

    int m = s_m;
    const bool over = (m > SLICE_CAP);
    if (over) m = SLICE_CAP;
    if (tid == 0) cntS[p * SPLIT + s] = over ? -1 : m;   // negative => overflow => fallback
    unsigned long long* my = cand + (size_t)(p * SPLIT + s) * SLICE_CAP;
    for (int i = tid; i < m; i += NTS) my[i] = buf[i];
}

// ---- Kernel 2: exact rank-K radix select per pair (LDS-cached candidates,
//      single-wave suffix-scan pick), fused with coverage via done-counter. ----
__global__ __launch_bounds__(NTS) void select_cov_kernel(const float* __restrict__ rv,
                                                         const float* __restrict__ ri,
                                                         const float* __restrict__ rf,
                                                         const int* __restrict__ cntS,
                                                         const unsigned long long* __restrict__ cand,
                                                         int* __restrict__ idx_out,
                                                         int* __restrict__ done,
                                                         float* __restrict__ out,
                                                         float inv_b) {
    const int p = blockIdx.x;
    const int t = p % 3;
    const int bb = p / 3;
    const int K = (t == 2) ? 360 : 180;
    int* obuf = idx_out + (size_t)p * 360;
    const int tid = threadIdx.x;

    __shared__ unsigned long long lc[LSEL];   // 16 KB candidate cache
    __shared__ unsigned hist[256];
    __shared__ int ties[TIE_CAP];
    __shared__ int soff[SPLIT]; __shared__ int scnt[SPLIT];
    __shared__ int s_total, s_bad;
    __shared__ unsigned s_p2; __shared__ int s_b2; __shared__ int s_cg2;
    __shared__ int s_on, s_tn, s_pickd; __shared__ unsigned s_pickb;
    __shared__ int s_prev;

    // slice counts -> offsets (wave 0, shfl scan; no barriers inside)
    if (tid < 64) {
        int c = (tid < SPLIT) ? cntS[p * SPLIT + tid] : 0;
        int bad = (c < 0) ? 1 : 0;
        int cc = bad ? 0 : c;
        int v = cc;
        #pragma unroll
        for (int off = 1; off < 64; off <<= 1) {
            int u = __shfl_up(v, off, 64);
            if (tid >= off) v += u;
        }
        if (tid < SPLIT) { soff[tid] = v - cc; scnt[tid] = cc; }
        if (tid == 63) s_total = v;
        unsigned long long bm = __ballot(bad != 0);
        if (tid == 0) s_bad = (bm != 0ull) ? 1 : 0;
    }
    __syncthreads();
    const int total = s_total;
    const bool fits = (!s_bad) && (total >= K) && (total <= LSEL);

    if (fits) {   // compact the 32 slices into lc[]: 8 threads per slice
        const int sl = tid >> 3;
        const int j0 = tid & 7;
        const unsigned long long* src = cand + (size_t)(p * SPLIT + sl) * SLICE_CAP;
        const int c = scnt[sl];
        const int o = soff[sl];
        for (int j = j0; j < c; j += 8) lc[o + j] = src[j];
    }
    __syncthreads();

    const float4* p4 = (const float4*)pairSrc(p, rv, ri, rf);

    if (tid == 0) { s_p2 = 0; s_b2 = 0; s_cg2 = 0; }
    __syncthreads();

    // 4 passes x 8 bits
    while (s_b2 < 32) {
        hist[tid] = 0;                        // NTS == 256
        __syncthreads();
        {
            const int b2 = s_b2; const unsigned p2 = s_p2;
            const int sh2 = 24 - b2;
            if (fits) {
                for (int i = tid; i < total; i += NTS) {
                    unsigned kk = (unsigned)(lc[i] >> 32);
                    bool match = (b2 == 0) || ((kk >> (32 - b2)) == p2);
                    if (match) atomicAdd(&hist[(kk >> sh2) & 255u], 1u);
                }
            } else {   // fallback: full-image scan (degenerate inputs only)
                for (int i = tid; i < N_ELEM / 4; i += NTS) {
                    float4 v = p4[i];
                    unsigned kk;
                    kk = keyOf(v.x); if ((b2 == 0) || ((kk >> (32 - b2)) == p2)) atomicAdd(&hist[(kk >> sh2) & 255u], 1u);
                    kk = keyOf(v.y); if ((b2 == 0) || ((kk >> (32 - b2)) == p2)) atomicAdd(&hist[(kk >> sh2) & 255u], 1u);
                    kk = keyOf(v.z); if ((b2 == 0) || ((kk >> (32 - b2)) == p2)) atomicAdd(&hist[(kk >> sh2) & 255u], 1u);
                    kk = keyOf(v.w); if ((b2 == 0) || ((kk >> (32 - b2)) == p2)) atomicAdd(&hist[(kk >> sh2) & 255u], 1u);
                }
            }
        }
        __syncthreads();
        const unsigned r = (unsigned)(K - s_cg2);
        if (tid < 64) {   // single-wave suffix-scan pick (4 bins/lane)
            const int l = tid;
            unsigned h0 = hist[4*l+0], h1 = hist[4*l+1], h2 = hist[4*l+2], h3 = hist[4*l+3];
            unsigned sum4 = h0 + h1 + h2 + h3;
            unsigned suf = sum4;
            #pragma unroll
            for (int off = 1; off < 64; off <<= 1) {
                unsigned u = __shfl_down(suf, off, 64);
                if (l + off < 64) suf += u;
            }
            unsigned s0 = suf, s1 = s0 - h0, s2 = s1 - h1, s3 = s2 - h2, s4 = s3 - h3;
            int d = -1; unsigned below = 0;
            if      (s3 >= r && s4 < r) { d = 4*l+3; below = s4; }
            else if (s2 >= r && s3 < r) { d = 4*l+2; below = s3; }
            else if (s1 >= r && s2 < r) { d = 4*l+1; below = s2; }
            else if (s0 >= r && s1 < r) { d = 4*l+0; below = s1; }
            if (d >= 0) { s_pickd = d; s_pickb = below; }   // exactly one lane
        }
        __syncthreads();
        if (tid == 0) {
            s_p2 = (s_p2 << 8) | (unsigned)s_pickd;
            s_cg2 += (int)s_pickb;
            s_b2 += 8;
        }
        __syncthreads();
    }

    if (tid == 0) { s_on = 0; s_tn = 0; }
    __syncthreads();

    // emit: key > Kth directly; key == Kth to tie buffer
    {
        const unsigned Kth = s_p2;
        if (fits) {
            for (int i = tid; i < total; i += NTS) {
                unsigned long long e = lc[i];
                unsigned kk = (unsigned)(e >> 32);
                int idx = (int)(e & 0xffffffffu);
                if (kk > Kth) { int pos = atomicAdd(&s_on, 1); obuf[pos] = idx; }
                else if (kk == Kth) { int pos = atomicAdd(&s_tn, 1); if (pos < TIE_CAP) ties[pos] = idx; }
            }
        } else {
            for (int i = tid; i < N_ELEM / 4; i += NTS) {
                float4 v = p4[i];
                float vals[4] = {v.x, v.y, v.z, v.w};
                for (int c = 0; c < 4; ++c) {
                    unsigned kk = keyOf(vals[c]);
                    if (kk > Kth) { int pos = atomicAdd(&s_on, 1); obuf[pos] = 4 * i + c; }
                    else if (kk == Kth) { int pos = atomicAdd(&s_tn, 1); if (pos < TIE_CAP) ties[pos] = 4 * i + c; }
                }
            }
        }
    }
    __syncthreads();
    if (tid == 0) {
        int need = K - s_cg2;                       // tie slots to fill (>=1)
        int tn = s_tn; if (tn > TIE_CAP) tn = TIE_CAP;
        int rr = need; if (rr > tn) rr = tn;        // safety clamp (degenerate only)
        for (int a = 0; a < rr; ++a) {              // selection sort: rr smallest indices
            int mb = a;
            for (int j = a + 1; j < tn; ++j) if (ties[j] < ties[mb]) mb = j;
            int tmp = ties[a]; ties[a] = ties[mb]; ties[mb] = tmp;
            obuf[s_on + a] = ties[a];
        }
        for (int a = rr; a < need; ++a) obuf[s_on + a] = (tn > 0) ? ties[0] : 0;
    }

    // ---- fused coverage: last of the 3 pair-blocks for batch bb runs it ----
    __threadfence();                   // release our obuf writes (all threads)
    __syncthreads();
    if (tid == 0) s_prev = atomicAdd(&done[bb], 1);
    __syncthreads();
    if (s_prev == 2) {
        __threadfence();               // acquire the other two pairs' writes
        __shared__ int cnd[360]; __shared__ int fy[360]; __shared__ int fx[360];
        __shared__ int s_u, s_c;
        const int* rvI = idx_out + (size_t)(bb * 3 + 0) * 360;
        const int* riI = idx_out + (size_t)(bb * 3 + 1) * 360;
        const int* rfI = idx_out + (size_t)(bb * 3 + 2) * 360;
        for (int i = tid; i < 180; i += NTS) { cnd[i] = rvI[i]; cnd[180 + i] = riI[i]; }
        for (int i = tid; i < 360; i += NTS) { int v = rfI[i]; fy[i] = v >> 9; fx[i] = v & 511; }
        if (tid == 0) { s_u = 0; s_c = 0; }
        __syncthreads();

        int myu = 0, myc = 0;
        for (int i = tid; i < 360; i += NTS) {
            const int v = cnd[i];
            const int y = v >> 9, x = v & 511;
            int dup = 0;
            #pragma unroll 8
            for (int j = 0; j < 360; ++j) dup |= (int)((j < i) & (cnd[j] == v));
            int cov = 0;
            #pragma unroll 8
            for (int j = 0; j < 360; ++j) {
                int dy = y - fy[j]; dy = (dy < 0) ? -dy : dy;
                int dx = x - fx[j]; dx = (dx < 0) ? -dx : dx;
                cov |= (int)((dy <= 3) & (dx <= 3));
            }
            if (!dup) { myu += 1; myc += cov; }
        }
        if (myu) atomicAdd(&s_u, myu);
        if (myc) atomicAdd(&s_c, myc);
        __syncthreads();
        if (tid == 0) {
            float denom = (float)(s_u > 0 ? s_u : 1);
            float loss = 1.0f - (float)s_c / denom;
            atomicAdd(out, loss * inv_b);
        }
    }
}

extern "C" void kernel_launch(void* const* d_in, const int* in_sizes, int n_in,
                              void* d_out, int out_size, void* d_ws, size_t ws_size,
                              hipStream_t stream) {
    const float* rv = (const float*)d_in[0];
    const float* ri = (const float*)d_in[1];
    const float* rf = (const float*)d_in[2];
    float* out = (float*)d_out;

    const int B = in_sizes[0] / N_ELEM;
    const int P = 3 * B;

    // workspace: cntS (P*SPLIT ints) | done (B ints) | idx_buf (P*360 ints) | cand
    char* ws = (char*)d_ws;
    int* cntS = (int*)ws;
    int* done = (int*)(ws + (size_t)P * SPLIT * 4);
    int* idx_buf = (int*)(ws + (size_t)P * SPLIT * 4 + (size_t)B * 4);
    size_t fixed = (size_t)P * SPLIT * 4 + (size_t)B * 4 + (size_t)P * 360 * 4;
    fixed = (fixed + 7) & ~(size_t)7;
    unsigned long long* cand = (unsigned long long*)(ws + fixed);
    // needs fixed + P*SPLIT*SLICE_CAP*8 bytes ~= 6.5 MB for B=32

    collect_kernel<<<P * SPLIT, NTS, 0, stream>>>(rv, ri, rf, cntS, cand, out, done, B);
    select_cov_kernel<<<P, NTS, 0, stream>>>(rv, ri, rf, cntS, cand, idx_buf, done, out, 1.0f / (float)B);
}

// Round 7
// 143.765 us; speedup vs baseline: 11.2117x; 1.1844x over previous
//
#include <hip/hip_runtime.h>

#define N_ELEM 262144   // 1*512*512 per batch image
#define SPLIT 32        // blocks per (batch,tensor) pair in collect
#define NTS 256         // block size
#define SLICE_CAP 256   // per-slice candidate cap (expected ~51, 28 sigma margin)
#define LSEL 2048       // select: LDS candidate cache entries (expected ~1630)
#define TIE_CAP 512
#define THRESH 2.5f     // fixed pre-filter; select falls back if counts invalid

// Order-preserving float->uint key: larger float => larger key.
__device__ __forceinline__ unsigned keyOf(float f) {
    unsigned u = __float_as_uint(f);
    return (u & 0x80000000u) ? ~u : (u | 0x80000000u);
}

__device__ __forceinline__ const float* pairSrc(int p, const float* rv, const float* ri, const float* rf) {
    int t = p % 3, b = p / 3;
    return (t == 0 ? rv : (t == 1 ? ri : rf)) + (size_t)b * N_ELEM;
}

// ---- Kernel 1: threshold-filter into PER-SLICE candidate regions.
//      No global atomics, no zeroing needed (counts written unconditionally).
//      Block 0 also zeroes out/done. ----
__global__ __launch_bounds__(NTS) void collect_kernel(const float* __restrict__ rv,
                                                      const float* __restrict__ ri,
                                                      const float* __restrict__ rf,
                                                      int* __restrict__ cntS,
                                                      unsigned long long* __restrict__ cand,
                                                      float* __restrict__ out,
                                                      int* __restrict__ done, int B) {
    const int p = blockIdx.x / SPLIT;
    const int s = blockIdx.x % SPLIT;
    const float4* p4 = (const float4*)pairSrc(p, rv, ri, rf) + (size_t)s * (N_ELEM / 4 / SPLIT);

    __shared__ unsigned long long buf[SLICE_CAP];   // 2 KB
    __shared__ int s_m;
    const int tid = threadIdx.x;

    if (blockIdx.x == 0) {            // once per launch: zero out + done[]
        if (tid < B) done[tid] = 0;
        if (tid == B) *out = 0.0f;
    }
    if (tid == 0) s_m = 0;
    __syncthreads();

    const int base_idx = s * (N_ELEM / SPLIT);
    for (int i = tid; i < N_ELEM / 4 / SPLIT; i += NTS) {   // 8 iterations
        float4 v = p4[i];
        int pos;
        if (v.x > THRESH) { pos = atomicAdd(&s_m, 1); if (pos < SLICE_CAP) buf[pos] = ((unsigned long long)keyOf(v.x) << 32) | (unsigned)(base_idx + 4 * i + 0); }
        if (v.y > THRESH) { pos = atomicAdd(&s_m, 1); if (pos < SLICE_CAP) buf[pos] = ((unsigned long long)keyOf(v.y) << 32) | (unsigned)(base_idx + 4 * i + 1); }
        if (v.z > THRESH) { pos = atomicAdd(&s_m, 1); if (pos < SLICE_CAP) buf[pos] = ((unsigned long long)keyOf(v.z) << 32) | (unsigned)(base_idx + 4 * i + 2); }
        if (v.w > THRESH) { pos = atomicAdd(&s_m, 1); if (pos < SLICE_CAP) buf[pos] = ((unsigned long long)keyOf(v.w) << 32) | (unsigned)(base_idx + 4 * i + 3); }
    }
    __syncthreads();

    int m = s_m;
    const bool over = (m > SLICE_CAP);
    if (over) m = SLICE_CAP;
    if (tid == 0) cntS[p * SPLIT + s] = over ? -1 : m;   // negative => overflow => fallback
    unsigned long long* my = cand + (size_t)(p * SPLIT + s) * SLICE_CAP;
    for (int i = tid; i < m; i += NTS) my[i] = buf[i];
}

// ---- Kernel 2: exact rank-K radix select per pair (LDS-cached candidates),
//      fused with bitmap coverage via per-batch done-counter. ----
// Shared-memory union (48 KB), temporally disjoint uses:
//   select phase:  lcKey[2048] (8K) | lcIdx[2048] (8K)         [first 16 KB]
//   coverage:      rfbm[8192] (32K) | srcbm[4096] (16K)        [all 48 KB]
__global__ __launch_bounds__(NTS) void select_cov_kernel(const float* __restrict__ rv,
                                                         const float* __restrict__ ri,
                                                         const float* __restrict__ rf,
                                                         const int* __restrict__ cntS,
                                                         const unsigned long long* __restrict__ cand,
                                                         int* __restrict__ idx_out,
                                                         int* __restrict__ done,
                                                         float* __restrict__ out,
                                                         float inv_b) {
    const int p = blockIdx.x;
    const int t = p % 3;
    const int bb = p / 3;
    const int K = (t == 2) ? 360 : 180;
    int* obuf = idx_out + (size_t)p * 360;
    const int tid = threadIdx.x;

    __shared__ __align__(16) unsigned char smem[49152];   // 48 KB union
    unsigned* lcKey = (unsigned*)smem;            // 8 KB
    unsigned* lcIdx = (unsigned*)(smem + 8192);   // 8 KB
    __shared__ unsigned hist[256];
    __shared__ int ties[TIE_CAP];
    __shared__ int soff[SPLIT]; __shared__ int scnt[SPLIT];
    __shared__ int s_total, s_bad;
    __shared__ unsigned s_p2; __shared__ int s_b2; __shared__ int s_cg2;
    __shared__ int s_on, s_tn, s_pickd; __shared__ unsigned s_pickb;
    __shared__ int s_prev, s_u, s_c;

    // slice counts -> offsets (wave 0, shfl scan; no barriers inside)
    if (tid < 64) {
        int c = (tid < SPLIT) ? cntS[p * SPLIT + tid] : 0;
        int bad = (c < 0) ? 1 : 0;
        int cc = bad ? 0 : c;
        int v = cc;
        #pragma unroll
        for (int off = 1; off < 64; off <<= 1) {
            int u = __shfl_up(v, off, 64);
            if (tid >= off) v += u;
        }
        if (tid < SPLIT) { soff[tid] = v - cc; scnt[tid] = cc; }
        if (tid == 63) s_total = v;
        unsigned long long bm = __ballot(bad != 0);
        if (tid == 0) s_bad = (bm != 0ull) ? 1 : 0;
    }
    __syncthreads();
    const int total = s_total;
    const bool fits = (!s_bad) && (total >= K) && (total <= LSEL);

    if (fits) {   // compact the 32 slices into lcKey/lcIdx: 8 threads per slice
        const int sl = tid >> 3;
        const int j0 = tid & 7;
        const unsigned long long* src = cand + (size_t)(p * SPLIT + sl) * SLICE_CAP;
        const int c = scnt[sl];
        const int o = soff[sl];
        for (int j = j0; j < c; j += 8) {
            unsigned long long e = src[j];
            lcKey[o + j] = (unsigned)(e >> 32);
            lcIdx[o + j] = (unsigned)(e & 0xffffffffu);
        }
    }
    __syncthreads();

    const float4* p4 = (const float4*)pairSrc(p, rv, ri, rf);

    if (tid == 0) { s_p2 = 0; s_b2 = 0; s_cg2 = 0; }
    __syncthreads();

    // 4 passes x 8 bits
    while (s_b2 < 32) {
        hist[tid] = 0;                        // NTS == 256
        __syncthreads();
        {
            const int b2 = s_b2; const unsigned p2 = s_p2;
            const int sh2 = 24 - b2;
            if (fits) {
                for (int i = tid; i < total; i += NTS) {
                    unsigned kk = lcKey[i];
                    bool match = (b2 == 0) || ((kk >> (32 - b2)) == p2);
                    if (match) atomicAdd(&hist[(kk >> sh2) & 255u], 1u);
                }
            } else {   // fallback: full-image scan (degenerate inputs only)
                for (int i = tid; i < N_ELEM / 4; i += NTS) {
                    float4 v = p4[i];
                    unsigned kk;
                    kk = keyOf(v.x); if ((b2 == 0) || ((kk >> (32 - b2)) == p2)) atomicAdd(&hist[(kk >> sh2) & 255u], 1u);
                    kk = keyOf(v.y); if ((b2 == 0) || ((kk >> (32 - b2)) == p2)) atomicAdd(&hist[(kk >> sh2) & 255u], 1u);
                    kk = keyOf(v.z); if ((b2 == 0) || ((kk >> (32 - b2)) == p2)) atomicAdd(&hist[(kk >> sh2) & 255u], 1u);
                    kk = keyOf(v.w); if ((b2 == 0) || ((kk >> (32 - b2)) == p2)) atomicAdd(&hist[(kk >> sh2) & 255u], 1u);
                }
            }
        }
        __syncthreads();
        const unsigned r = (unsigned)(K - s_cg2);
        if (tid < 64) {   // single-wave suffix-scan pick (4 bins/lane)
            const int l = tid;
            unsigned h0 = hist[4*l+0], h1 = hist[4*l+1], h2 = hist[4*l+2], h3 = hist[4*l+3];
            unsigned sum4 = h0 + h1 + h2 + h3;
            unsigned suf = sum4;
            #pragma unroll
            for (int off = 1; off < 64; off <<= 1) {
                unsigned u = __shfl_down(suf, off, 64);
                if (l + off < 64) suf += u;
            }
            unsigned s0 = suf, s1 = s0 - h0, s2 = s1 - h1, s3 = s2 - h2, s4 = s3 - h3;
            int d = -1; unsigned below = 0;
            if      (s3 >= r && s4 < r) { d = 4*l+3; below = s4; }
            else if (s2 >= r && s3 < r) { d = 4*l+2; below = s3; }
            else if (s1 >= r && s2 < r) { d = 4*l+1; below = s2; }
            else if (s0 >= r && s1 < r) { d = 4*l+0; below = s1; }
            if (d >= 0) { s_pickd = d; s_pickb = below; }   // exactly one lane
        }
        __syncthreads();
        if (tid == 0) {
            s_p2 = (s_p2 << 8) | (unsigned)s_pickd;
            s_cg2 += (int)s_pickb;
            s_b2 += 8;
        }
        __syncthreads();
    }

    if (tid == 0) { s_on = 0; s_tn = 0; }
    __syncthreads();

    // emit: key > Kth directly; key == Kth to tie buffer
    {
        const unsigned Kth = s_p2;
        if (fits) {
            for (int i = tid; i < total; i += NTS) {
                unsigned kk = lcKey[i];
                int idx = (int)lcIdx[i];
                if (kk > Kth) { int pos = atomicAdd(&s_on, 1); obuf[pos] = idx; }
                else if (kk == Kth) { int pos = atomicAdd(&s_tn, 1); if (pos < TIE_CAP) ties[pos] = idx; }
            }
        } else {
            for (int i = tid; i < N_ELEM / 4; i += NTS) {
                float4 v = p4[i];
                float vals[4] = {v.x, v.y, v.z, v.w};
                for (int c = 0; c < 4; ++c) {
                    unsigned kk = keyOf(vals[c]);
                    if (kk > Kth) { int pos = atomicAdd(&s_on, 1); obuf[pos] = 4 * i + c; }
                    else if (kk == Kth) { int pos = atomicAdd(&s_tn, 1); if (pos < TIE_CAP) ties[pos] = 4 * i + c; }
                }
            }
        }
    }
    __syncthreads();
    if (tid == 0) {
        int need = K - s_cg2;                       // tie slots to fill (>=1)
        int tn = s_tn; if (tn > TIE_CAP) tn = TIE_CAP;
        int rr = need; if (rr > tn) rr = tn;        // safety clamp (degenerate only)
        for (int a = 0; a < rr; ++a) {              // selection sort: rr smallest indices
            int mb = a;
            for (int j = a + 1; j < tn; ++j) if (ties[j] < ties[mb]) mb = j;
            int tmp = ties[a]; ties[a] = ties[mb]; ties[mb] = tmp;
            obuf[s_on + a] = ties[a];
        }
        for (int a = rr; a < need; ++a) obuf[s_on + a] = (tn > 0) ? ties[0] : 0;
    }

    // ---- fused coverage (bitmap version): last pair-block of batch bb ----
    __threadfence();                   // release our obuf writes
    __syncthreads();                   // also: last read of lcKey/lcIdx before aliasing
    if (tid == 0) s_prev = atomicAdd(&done[bb], 1);
    __syncthreads();
    if (s_prev == 2) {
        __threadfence();               // acquire the other two pairs' writes
        unsigned* rfbm  = (unsigned*)smem;             // 32 KB: 512 rows x 16 words
        unsigned* srcbm = (unsigned*)(smem + 32768);   // 16 KB: one y-half
        const int* rvI = idx_out + (size_t)(bb * 3 + 0) * 360;
        const int* riI = idx_out + (size_t)(bb * 3 + 1) * 360;
        const int* rfI = idx_out + (size_t)(bb * 3 + 2) * 360;

        for (int i = tid; i < 8192; i += NTS) rfbm[i] = 0;
        if (tid == 0) { s_u = 0; s_c = 0; }
        __syncthreads();
        for (int i = tid; i < 360; i += NTS) {
            int v = rfI[i];
            atomicOr(&rfbm[v >> 5], 1u << (v & 31));
        }
        __syncthreads();

        int myu = 0, myc = 0;
        for (int h = 0; h < 2; ++h) {              // two y-halves share the 16 KB srcbm
            for (int i = tid; i < 4096; i += NTS) srcbm[i] = 0;
            __syncthreads();
            for (int i = tid; i < 360; i += NTS) {
                int v = (i < 180) ? rvI[i] : riI[i - 180];
                int y = v >> 9, x = v & 511;
                if ((y >> 8) == h) {
                    unsigned bit = 1u << (v & 31);
                    unsigned old = atomicOr(&srcbm[(v >> 5) & 4095], bit);
                    if (!(old & bit)) {            // unique in the union set
                        myu++;
                        int lo = x - 3; if (lo < 0) lo = 0;
                        int hi = x + 3; if (hi > 511) hi = 511;
                        int k0 = lo >> 5, k1 = hi >> 5;
                        unsigned m0, m1;
                        if (k0 == k1) { m0 = ((1u << (hi - lo + 1)) - 1u) << (lo & 31); m1 = 0u; }
                        else          { m0 = 0xffffffffu << (lo & 31); m1 = (1u << ((hi & 31) + 1)) - 1u; }
                        unsigned cov = 0;
                        #pragma unroll
                        for (int dy = -3; dy <= 3; ++dy) {
                            int yy = y + dy;
                            if (yy >= 0 && yy < 512) {
                                const unsigned* row = &rfbm[yy << 4];
                                cov |= (row[k0] & m0);
                                if (k1 != k0) cov |= (row[k1] & m1);
                            }
                        }
                        myc += (cov != 0u) ? 1 : 0;
                    }
                }
            }
            __syncthreads();
        }
        if (myu) atomicAdd(&s_u, myu);
        if (myc) atomicAdd(&s_c, myc);
        __syncthreads();
        if (tid == 0) {
            float denom = (float)(s_u > 0 ? s_u : 1);
            float loss = 1.0f - (float)s_c / denom;
            atomicAdd(out, loss * inv_b);
        }
    }
}

extern "C" void kernel_launch(void* const* d_in, const int* in_sizes, int n_in,
                              void* d_out, int out_size, void* d_ws, size_t ws_size,
                              hipStream_t stream) {
    const float* rv = (const float*)d_in[0];
    const float* ri = (const float*)d_in[1];
    const float* rf = (const float*)d_in[2];
    float* out = (float*)d_out;

    const int B = in_sizes[0] / N_ELEM;
    const int P = 3 * B;

    // workspace: cntS (P*SPLIT ints) | done (B ints) | idx_buf (P*360 ints) | cand
    char* ws = (char*)d_ws;
    int* cntS = (int*)ws;
    int* done = (int*)(ws + (size_t)P * SPLIT * 4);
    int* idx_buf = (int*)(ws + (size_t)P * SPLIT * 4 + (size_t)B * 4);
    size_t fixed = (size_t)P * SPLIT * 4 + (size_t)B * 4 + (size_t)P * 360 * 4;
    fixed = (fixed + 7) & ~(size_t)7;
    unsigned long long* cand = (unsigned long long*)(ws + fixed);
    // needs fixed + P*SPLIT*SLICE_CAP*8 bytes ~= 6.5 MB for B=32

    collect_kernel<<<P * SPLIT, NTS, 0, stream>>>(rv, ri, rf, cntS, cand, out, done, B);
    select_cov_kernel<<<P, NTS, 0, stream>>>(rv, ri, rf, cntS, cand, idx_buf, done, out, 1.0f / (float)B);
}